// Round 8
// baseline (723.016 us; speedup 1.0000x reference)
//
#include <hip/hip_runtime.h>
#include <hip/hip_bf16.h>

typedef __bf16 bf16;
typedef __attribute__((ext_vector_type(4))) int intx4;
typedef __attribute__((ext_vector_type(4))) float floatx4;
typedef __attribute__((ext_vector_type(8))) unsigned short ushortx8;

__device__ __forceinline__ float b2f(unsigned short u) {
  union { unsigned int i; float f; } v; v.i = ((unsigned int)u) << 16; return v.f;
}

__device__ __forceinline__ void async_copy16(const void* g, void* l) {
  __builtin_amdgcn_global_load_lds((__attribute__((address_space(1))) void*)(g),
                                   (__attribute__((address_space(3))) void*)(l),
                                   16, 0, 0);
}

__device__ __forceinline__ float warp_sum(float v) {
  #pragma unroll
  for (int off = 32; off > 0; off >>= 1) v += __shfl_xor(v, off, 64);
  return v;
}
__device__ __forceinline__ float warp_max(float v) {
  #pragma unroll
  for (int off = 32; off > 0; off >>= 1) v = fmaxf(v, __shfl_xor(v, off, 64));
  return v;
}

// exact-erf GELU via A&S 7.1.26 (|eps| <= 1.5e-7), hw rcp + exp
__device__ __forceinline__ float gelu_fast(float v) {
  const float a = fabsf(v) * 0.70710678118654752440f;
  const float t = __builtin_amdgcn_rcpf(fmaf(0.3275911f, a, 1.0f));
  const float e = __expf(-a * a);
  float p = fmaf(1.061405429f, t, -1.453152027f);
  p = fmaf(p, t, 1.421413741f);
  p = fmaf(p, t, -0.284496736f);
  p = fmaf(p, t, 0.254829592f);
  float erfa = fmaf(-p * t, e, 1.0f);          // erf(|v|/sqrt2)
  erfa = copysignf(erfa, v);
  return 0.5f * v * (1.0f + erfa);
}

// clamp+round+pack 4 floats to 4 int8 in a u32 (activation quant, [-128,127])
__device__ __forceinline__ unsigned int pack4(float a, float b, float c, float d,
                                              float sc) {
  const int ia = (int)fminf(fmaxf(rintf(a * sc), -128.f), 127.f);
  const int ib = (int)fminf(fmaxf(rintf(b * sc), -128.f), 127.f);
  const int ic = (int)fminf(fmaxf(rintf(c * sc), -128.f), 127.f);
  const int id = (int)fminf(fmaxf(rintf(d * sc), -128.f), 127.f);
  return (unsigned)(ia & 255) | ((unsigned)(ib & 255) << 8) |
         ((unsigned)(ic & 255) << 16) | ((unsigned)(id & 255) << 24);
}

// ---------------- weight absmean (both tensors in one launch) ----------------
__global__ __launch_bounds__(256) void absmean2(const float* __restrict__ w1,
                                                const float* __restrict__ w2, int n,
                                                float* __restrict__ p1,
                                                float* __restrict__ p2) {
  const int half = blockIdx.x >> 8;     // grid = 512: 0..255 -> w1, 256..511 -> w2
  const int b = blockIdx.x & 255;
  const float* __restrict__ w = half ? w2 : w1;
  const int tid = threadIdx.x;
  const int lane = tid & 63, wave = tid >> 6;
  float s = 0.f;
  for (size_t i = ((size_t)b * 256 + tid) * 4; i < (size_t)n;
       i += (size_t)256 * 256 * 4) {
    float4 u = *(const float4*)(w + i);
    s += fabsf(u.x) + fabsf(u.y) + fabsf(u.z) + fabsf(u.w);
  }
  __shared__ float red[4];
  s = warp_sum(s);
  if (lane == 0) red[wave] = s;
  __syncthreads();
  if (tid == 0) (half ? p2 : p1)[b] = red[0] + red[1] + red[2] + red[3];
}

// scales: [0]=s_w1 (quant), [1]=dq_w1, [2]=s_w2, [3]=dq_w2
__global__ __launch_bounds__(256) void finalize_scales(const float* __restrict__ p1,
                                                       const float* __restrict__ p2,
                                                       float inv_n1, float inv_n2,
                                                       float* __restrict__ scales) {
  const int tid = threadIdx.x;
  const int lane = tid & 63, wave = tid >> 6;
  float a = p1[tid], b = p2[tid];
  a = warp_sum(a); b = warp_sum(b);
  __shared__ float red[8];
  if (lane == 0) { red[wave] = a; red[4 + wave] = b; }
  __syncthreads();
  if (tid == 0) {
    float m1 = fmaxf((red[0] + red[1] + red[2] + red[3]) * inv_n1, 1e-5f);
    float m2 = fmaxf((red[4] + red[5] + red[6] + red[7]) * inv_n2, 1e-5f);
    scales[0] = 1.0f / m1; scales[1] = m1;
    scales[2] = 1.0f / m2; scales[3] = m2;
  }
}

// ternarize both fp32 weight tensors -> int8 {-1,0,1} in one launch.
// NB: weight quant clamps to [-1,1] (ternary), NOT [-128,127].
__global__ __launch_bounds__(256) void quant_w2(const float* __restrict__ w1,
                                                const float* __restrict__ w2,
                                                signed char* __restrict__ q1,
                                                signed char* __restrict__ q2,
                                                const float* __restrict__ scales,
                                                int nb, int n) {
  const int bid = blockIdx.x;
  const int second = bid >= nb;
  const float* __restrict__ w = second ? w2 : w1;
  signed char* __restrict__ q = second ? q2 : q1;
  const float s = scales[second * 2];
  const int i4 = ((second ? bid - nb : bid) * 256 + (int)threadIdx.x) * 4;
  if (i4 >= n) return;
  float4 u = *(const float4*)(w + i4);
  char4 o;
  o.x = (signed char)fminf(fmaxf(rintf(u.x * s), -1.f), 1.f);
  o.y = (signed char)fminf(fmaxf(rintf(u.y * s), -1.f), 1.f);
  o.z = (signed char)fminf(fmaxf(rintf(u.z * s), -1.f), 1.f);
  o.w = (signed char)fminf(fmaxf(rintf(u.w * s), -1.f), 1.f);
  *(char4*)(q + i4) = o;
}

// ---------------- [gelu] + layernorm + per-row int8 quant ----------------
// grid-stride over rows (2048 blocks); gamma/beta hoisted to registers once per
// block; 16B vector loads; packed int8 stores. (R6 version, unchanged.)
template <int D, bool GELU, typename XT>
__global__ __launch_bounds__(256) void ln_quant_kernel(const XT* __restrict__ x,
                                                       const float* __restrict__ gam,
                                                       const float* __restrict__ bet,
                                                       signed char* __restrict__ q,
                                                       float* __restrict__ rdq,
                                                       int px, int pq, int nrows) {
  constexpr int VE = (sizeof(XT) == 4) ? 4 : 8;   // elems per 16B load
  constexpr int NV = D / (256 * VE);
  const int tid = threadIdx.x;
  const int lane = tid & 63, wave = tid >> 6;
  float gg[NV * VE], bb[NV * VE];
  #pragma unroll
  for (int v = 0; v < NV; ++v) {
    #pragma unroll
    for (int k = 0; k < VE; k += 4) {
      const int idx = v * (256 * VE) + tid * VE + k;
      float4 gv = *(const float4*)(gam + idx);
      float4 bv = *(const float4*)(bet + idx);
      gg[v * VE + k + 0] = gv.x; gg[v * VE + k + 1] = gv.y;
      gg[v * VE + k + 2] = gv.z; gg[v * VE + k + 3] = gv.w;
      bb[v * VE + k + 0] = bv.x; bb[v * VE + k + 1] = bv.y;
      bb[v * VE + k + 2] = bv.z; bb[v * VE + k + 3] = bv.w;
    }
  }
  __shared__ float red[12];
  const float inv_d = 1.0f / (float)D;
  for (int row = blockIdx.x; row < nrows; row += gridDim.x) {
    const size_t xbase = (size_t)row * px;
    const size_t qbase = (size_t)row * pq;
    float y[NV * VE];
    float s = 0.f, ss = 0.f;
    #pragma unroll
    for (int v = 0; v < NV; ++v) {
      const int idx = v * (256 * VE) + tid * VE;
      if constexpr (sizeof(XT) == 4) {
        float4 u = *(const float4*)(x + xbase + idx);
        float vv[4] = {u.x, u.y, u.z, u.w};
        #pragma unroll
        for (int j = 0; j < 4; ++j) {
          float t = GELU ? gelu_fast(vv[j]) : vv[j];
          y[v * VE + j] = t; s += t; ss += t * t;
        }
      } else {
        ushortx8 u = *(const ushortx8*)(x + xbase + idx);
        #pragma unroll
        for (int j = 0; j < 8; ++j) {
          float t = b2f(u[j]);
          t = GELU ? gelu_fast(t) : t;
          y[v * VE + j] = t; s += t; ss += t * t;
        }
      }
    }
    float sw = warp_sum(s), qw = warp_sum(ss);
    if (lane == 0) { red[wave] = sw; red[4 + wave] = qw; }
    __syncthreads();
    const float mu = (red[0] + red[1] + red[2] + red[3]) * inv_d;
    const float var = (red[4] + red[5] + red[6] + red[7]) * inv_d - mu * mu;
    const float rstd = rsqrtf(var + 1e-5f);
    float amax = 0.f;
    #pragma unroll
    for (int i = 0; i < NV * VE; ++i) {
      float yy = (y[i] - mu) * rstd * gg[i] + bb[i];
      y[i] = yy;
      amax = fmaxf(amax, fabsf(yy));
    }
    float wm = warp_max(amax);
    if (lane == 0) red[8 + wave] = wm;
    __syncthreads();
    const float am = fmaxf(fmaxf(fmaxf(red[8], red[9]), fmaxf(red[10], red[11])), 1e-5f);
    const float sc = 127.0f / am;
    #pragma unroll
    for (int v = 0; v < NV; ++v) {
      const int idx = v * (256 * VE) + tid * VE;
      if constexpr (sizeof(XT) == 4) {
        *(unsigned int*)(q + qbase + idx) =
            pack4(y[v * VE + 0], y[v * VE + 1], y[v * VE + 2], y[v * VE + 3], sc);
      } else {
        uint2 o;
        o.x = pack4(y[v * VE + 0], y[v * VE + 1], y[v * VE + 2], y[v * VE + 3], sc);
        o.y = pack4(y[v * VE + 4], y[v * VE + 5], y[v * VE + 6], y[v * VE + 7], sc);
        *(uint2*)(q + qbase + idx) = o;
      }
    }
    if (tid == 0) rdq[row] = am * (1.0f / 127.0f);
  }
}

// ---------------- int8 GEMM, 256x256 tile, 2-phase-per-K-tile ----------------
// Per K-tile (128B = 2 kslots), 2 phases; each phase = {12 ds_read_b128 (full
// kslot), stage one kslot pair (4 copies), barrier, lgkmcnt(0), 32 MFMA,
// barrier}. Sync events/tile: 5 (vs 10 in R3's 4-phase). In-loop S1/S2 are
// ALWAYS true (R7's tail predicate `t+1 < NT-3` dropped tile NT-1's ks0 stage
// -> absmax 1.64; the second call's S2 stages t+3 <= NT-1 for every in-loop t).
// vmcnt ledger: entry 4 outstanding (next tile ks0); A +4 (t+1 ks1) -> 8;
// B +4 (t+2 ks0) -> 12; vmcnt(4) retires tile t+1's 8. Tails drain with 0.
// WAR: ks0 readers retire at phase-A lgkmcnt(0) before its trailing barrier,
// which precedes the phase-B overwrite issue. T1/T2/T5 retained.

#define RD_A(DST, MH, KS, BUF)                                               \
  _Pragma("unroll") for (int mi = 0; mi < 4; ++mi) {                         \
    DST[mi] = *(const intx4*)&lds[(BUF) * 65536 + (KS) * 16384 + aoff +      \
                                  ((MH) * 4 + mi) * 1024];                   \
  }

#define RD_B(DST, KS, BUF)                                                   \
  _Pragma("unroll") for (int ni = 0; ni < 4; ++ni) {                         \
    DST[ni] = *(const intx4*)&lds[(BUF) * 65536 + 32768 + (KS) * 16384 +     \
                                  boff + ni * 1024];                         \
  }

#define MFMA32()                                                             \
  __builtin_amdgcn_s_setprio(1);                                             \
  _Pragma("unroll") for (int mi = 0; mi < 4; ++mi) {                         \
    _Pragma("unroll") for (int ni = 0; ni < 4; ++ni) {                       \
      acc[mi][ni] = __builtin_amdgcn_mfma_i32_16x16x64_i8(                   \
          aR0[mi], bR[ni], acc[mi][ni], 0, 0, 0);                            \
    }                                                                        \
  }                                                                          \
  _Pragma("unroll") for (int mi = 0; mi < 4; ++mi) {                         \
    _Pragma("unroll") for (int ni = 0; ni < 4; ++ni) {                       \
      acc[4 + mi][ni] = __builtin_amdgcn_mfma_i32_16x16x64_i8(               \
          aR1[mi], bR[ni], acc[4 + mi][ni], 0, 0, 0);                        \
    }                                                                        \
  }                                                                          \
  __builtin_amdgcn_s_setprio(0);

#define TILE2(T, BUF, S1, S2, VM)                                            \
  do {                                                                       \
    /* phase A: kslot 0 */                                                   \
    RD_A(aR0, 0, 0, BUF);                                                    \
    RD_A(aR1, 1, 0, BUF);                                                    \
    RD_B(bR, 0, BUF);                                                        \
    if (S1) { stageA((T) + 1, 1, (BUF) ^ 1); stageB((T) + 1, 1, (BUF) ^ 1); }\
    __builtin_amdgcn_s_barrier();                                            \
    asm volatile("s_waitcnt lgkmcnt(0)" ::: "memory");                       \
    MFMA32();                                                                \
    __builtin_amdgcn_s_barrier();                                            \
    /* phase B: kslot 1 */                                                   \
    RD_A(aR0, 0, 1, BUF);                                                    \
    RD_A(aR1, 1, 1, BUF);                                                    \
    RD_B(bR, 1, BUF);                                                        \
    if (S2) { stageA((T) + 2, 0, BUF); stageB((T) + 2, 0, BUF); }            \
    __builtin_amdgcn_s_barrier();                                            \
    asm volatile("s_waitcnt lgkmcnt(0)" ::: "memory");                       \
    MFMA32();                                                                \
    asm volatile("s_waitcnt vmcnt(" #VM ")" ::: "memory");                   \
    __builtin_amdgcn_s_barrier();                                            \
  } while (0)

template <typename CT>
__global__ __launch_bounds__(512, 2) void gemm_i8(const signed char* __restrict__ A,
                                                  const signed char* __restrict__ B,
                                                  CT* __restrict__ C,
                                                  const float* __restrict__ rdq,
                                                  const float* __restrict__ wdq_ptr,
                                                  const float* __restrict__ bias,
                                                  int N, int KB, int lda, int ldc) {
  __shared__ __align__(16) signed char lds[131072];
  const int tid = threadIdx.x;
  const int wave = tid >> 6, lane = tid & 63;
  const int quad = lane >> 4, l16 = lane & 15;
  const int nb = N >> 8;
  // T1: consecutive tile ids -> same XCD
  const int cpx = (int)gridDim.x >> 3;
  const int wg = (int)blockIdx.x;
  const int tile = (wg & 7) * cpx + (wg >> 3);
  const int bm = tile / nb;
  const int bn = tile % nb;
  const int wm = wave >> 2, wn = wave & 3;

  // staging: per half (16KB = 1024 chunks of 16B), thread handles chunks ch0, ch1.
  // chunk ch = row*4 + slot; global slot pre-swizzled: slot ^ ((row>>1)&3),
  // and (4*row+slot)>>3 == row>>1 exactly.
  const int ch0 = wave * 128 + lane;
  const int ch1 = ch0 + 64;
  const int g0 = ((ch0 & 3) ^ ((ch0 >> 3) & 3)) * 16;
  const int g1 = ((ch1 & 3) ^ ((ch1 >> 3) & 3)) * 16;
  const signed char* a0 = A + (size_t)(bm * 256 + (ch0 >> 2)) * lda + g0;
  const signed char* a1 = A + (size_t)(bm * 256 + (ch1 >> 2)) * lda + g1;
  const signed char* b0 = B + (size_t)(bn * 256 + (ch0 >> 2)) * KB + g0;
  const signed char* b1 = B + (size_t)(bn * 256 + (ch1 >> 2)) * KB + g1;

  auto stageA = [&](int t, int ks, int b) {
    signed char* d = &lds[b * 65536 + ks * 16384 + wave * 2048];
    const int off = t * 128 + ks * 64;
    async_copy16(a0 + off, d);
    async_copy16(a1 + off, d + 1024);
  };
  auto stageB = [&](int t, int ks, int b) {
    signed char* d = &lds[b * 65536 + 32768 + ks * 16384 + wave * 2048];
    const int off = t * 128 + ks * 64;
    async_copy16(b0 + off, d);
    async_copy16(b1 + off, d + 1024);
  };

  // ds_read addressing: row = (wm*128|wn*64) + (frag)*16 + l16; byte = row*64 + rsl.
  // row parity bits reduce to (l16>>1)&3 for every frag (others are 0 mod 4).
  const int rsl = (quad ^ ((l16 >> 1) & 3)) * 16;
  const int aoff = (wm * 128 + l16) * 64 + rsl;  // + (MH*4+mi)*1024
  const int boff = (wn * 64 + l16) * 64 + rsl;   // + ni*1024

  intx4 acc[8][4];
  #pragma unroll
  for (int i = 0; i < 8; ++i)
    #pragma unroll
    for (int j = 0; j < 4; ++j) acc[i][j] = (intx4){0, 0, 0, 0};
  intx4 aR0[4], aR1[4], bR[4];

  const float wdq = *wdq_ptr;
  const int NT = KB >> 7;  // 128B K-tiles; NT even (8 or 32)

  // prologue: tile0 both kslots + tile1 ks0; leave tile1's ks0 (4 copies) flying
  stageA(0, 0, 0); stageB(0, 0, 0);
  stageA(0, 1, 0); stageB(0, 1, 0);
  stageA(1, 0, 1); stageB(1, 0, 1);
  asm volatile("s_waitcnt vmcnt(4)" ::: "memory");
  __builtin_amdgcn_s_barrier();

  for (int t = 0; t < NT - 2; t += 2) {
    TILE2(t, 0, true, true, 4);
    TILE2(t + 1, 1, true, true, 4);
  }
  TILE2(NT - 2, 0, true, false, 0);
  TILE2(NT - 1, 1, false, false, 0);

  // epilogue: C/D layout col=lane&15, row=quad*4+reg (shape-determined, m121-128)
  #pragma unroll
  for (int mi = 0; mi < 8; ++mi) {
    const int rowb = bm * 256 + wm * 128 + mi * 16 + quad * 4;
    const floatx4 rd = *(const floatx4*)&rdq[rowb];
    #pragma unroll
    for (int ni = 0; ni < 4; ++ni) {
      const int col = bn * 256 + wn * 64 + ni * 16 + l16;
      const float bv = bias[col];
      #pragma unroll
      for (int r2 = 0; r2 < 4; ++r2) {
        float v = fmaf((float)acc[mi][ni][r2], rd[r2] * wdq, bv);
        C[(size_t)(rowb + r2) * ldc + col] = (CT)v;
      }
    }
  }
}

extern "C" void kernel_launch(void* const* d_in, const int* in_sizes, int n_in,
                              void* d_out, int out_size, void* d_ws, size_t ws_size,
                              hipStream_t stream) {
  (void)in_sizes; (void)n_in; (void)out_size; (void)ws_size;
  const float* x   = (const float*)d_in[0];
  const float* g1  = (const float*)d_in[1];
  const float* be1 = (const float*)d_in[2];
  const float* w1  = (const float*)d_in[3];
  const float* b1  = (const float*)d_in[4];
  const float* g2  = (const float*)d_in[5];
  const float* be2 = (const float*)d_in[6];
  const float* w2  = (const float*)d_in[7];
  const float* b2  = (const float*)d_in[8];
  float* out = (float*)d_out;

  const int BT = 8 * 4096, D = 1024, H = 4096;
  char* ws = (char*)d_ws;
  float* scales = (float*)(ws);                 // 4 floats
  float* p1     = (float*)(ws + 1024);
  float* p2     = (float*)(ws + 2048);
  float* rdq1   = (float*)(ws + 4096);          // 32768 fp32
  float* rdq2   = (float*)(ws + 4096 + 131072);
  char* big = ws + (1 << 20);
  signed char* w1q = (signed char*)(big);                 // 4 MB
  signed char* w2q = (signed char*)(big + (4 << 20));     // 4 MB
  signed char* qx1 = (signed char*)(big + (8 << 20));     // 32 MB
  bf16* h1 = (bf16*)(big + (40 << 20));                   // 256 MB -> total ~297 MB

  const int NW = H * D;
  absmean2<<<512, 256, 0, stream>>>(w1, w2, NW, p1, p2);
  finalize_scales<<<1, 256, 0, stream>>>(p1, p2, 1.0f / NW, 1.0f / NW, scales);
  quant_w2<<<2 * (NW / 1024), 256, 0, stream>>>(w1, w2, w1q, w2q, scales,
                                                NW / 1024, NW);

  // LN1 + act quant -> int8 (grid-stride over rows)
  ln_quant_kernel<1024, false, float><<<2048, 256, 0, stream>>>(x, g1, be1, qx1, rdq1,
                                                                D, D, BT);
  // GEMM1: h1(bf16) = dequant(qx1 . w1q^T) + b1   (pre-GELU; GELU fused into LN2)
  gemm_i8<bf16><<<(BT / 256) * (H / 256), 512, 0, stream>>>(
      qx1, w1q, h1, rdq1, scales + 1, b1, H, D, D, H);
  // GELU + LN2 + act quant, int8 written in-place into h1 row starts (pitch 8192 B)
  ln_quant_kernel<4096, true, bf16><<<2048, 256, 0, stream>>>(
      h1, g2, be2, (signed char*)h1, rdq2, H, 2 * H, BT);
  // GEMM2: out(fp32) = dequant(q . w2q^T) + b2
  gemm_i8<float><<<(BT / 256) * (D / 256), 512, 0, stream>>>(
      (signed char*)h1, w2q, out, rdq2, scales + 3, b2, D, H, 2 * H, D);
}